// Round 1
// 81.671 us; speedup vs baseline: 1.0252x; 1.0252x over previous
//
#include <hip/hip_runtime.h>

#define B_ROWS 32768
#define D_DIM  256
#define N_NEUR 256
#define DEG    8
#define F_FEAT (D_DIM * (DEG + 1))  // 2304
#define F4     (F_FEAT / 4)         // 576

// Stage 1: w[f] = sum_n coeffs[n,f] * h[n].
// 9 blocks x 1024 threads (16 waves). Block bx owns float4-slice [64*bx, 64*bx+64).
// Wave wv accumulates neurons [16*wv, 16*wv+16); LDS reduce across waves.
// Direct store: no memset dispatch, no atomics.
__global__ __launch_bounds__(1024) void reduce_w_kernel(
    const float* __restrict__ coeffs, const float* __restrict__ h,
    float* __restrict__ w) {
  __shared__ float4 part[16][64];
  const int lane = threadIdx.x & 63;
  const int wv   = threadIdx.x >> 6;
  const float4* c4 = (const float4*)coeffs;
  const int f4 = blockIdx.x * 64 + lane;

  float4 a = make_float4(0.f, 0.f, 0.f, 0.f);
#pragma unroll
  for (int j = 0; j < 16; ++j) {
    int n = wv * 16 + j;
    float hn = h[n];
    float4 c = c4[(size_t)n * F4 + f4];
    a.x = fmaf(c.x, hn, a.x);
    a.y = fmaf(c.y, hn, a.y);
    a.z = fmaf(c.z, hn, a.z);
    a.w = fmaf(c.w, hn, a.w);
  }
  part[wv][lane] = a;
  __syncthreads();

  if (threadIdx.x < 64) {
    float4 s = part[0][lane];
#pragma unroll
    for (int q = 1; q < 16; ++q) {
      float4 p = part[q][lane];
      s.x += p.x; s.y += p.y; s.z += p.z; s.w += p.w;
    }
    ((float4*)w)[f4] = s;
  }
}

// Stage 2: out[b] = sum_d sum_k T_k(tanh(x[b,d])) * w[9d+k]
// One wave per 4 consecutive rows. Lane l owns dims 4l..4l+3.
// Per-lane 36 w coeffs in registers, loaded once per block.
__global__ __launch_bounds__(256) void kan_main_kernel(
    const float* __restrict__ x, const float* __restrict__ w,
    float* __restrict__ out) {
  const int lane = threadIdx.x & 63;

  float wreg[36];  // wreg[9i+k] = w[36*lane + 9i + k]; dim 4l+i uses wreg[9i..9i+8]
  const float4* w4 = (const float4*)w;
#pragma unroll
  for (int q = 0; q < 9; ++q) {
    float4 v = w4[9 * lane + q];
    wreg[4 * q + 0] = v.x;
    wreg[4 * q + 1] = v.y;
    wreg[4 * q + 2] = v.z;
    wreg[4 * q + 3] = v.w;
  }

  const int gw = (int)((blockIdx.x * blockDim.x + threadIdx.x) >> 6);  // 0..8191
  const int r0 = gw * 4;                                               // 4 rows/wave

  // Issue all 4 row-loads up front (independent dwordx4 -> latency overlap).
  const float4* xr = (const float4*)(x + (size_t)r0 * D_DIM);
  float4 xv[4];
#pragma unroll
  for (int r = 0; r < 4; ++r) xv[r] = xr[r * 64 + lane];

  float acc[4];
#pragma unroll
  for (int r = 0; r < 4; ++r) {
    float xa[4] = {xv[r].x, xv[r].y, xv[r].z, xv[r].w};
    float s4 = 0.f;
#pragma unroll
    for (int i = 0; i < 4; ++i) {
      // fast tanh: t = 1 - 2/(exp(2x)+1)
      float e   = __expf(xa[i] + xa[i]);
      float rcp = __builtin_amdgcn_rcpf(e + 1.f);
      float t   = fmaf(-2.f, rcp, 1.f);
      float t2  = t + t;
      const float* wd = &wreg[9 * i];
      float s    = fmaf(t, wd[1], wd[0]);
      float tkm1 = 1.f, tk = t;
#pragma unroll
      for (int k = 2; k <= DEG; ++k) {
        float tn = fmaf(t2, tk, -tkm1);  // T_k = 2x*T_{k-1} - T_{k-2}
        s    = fmaf(tn, wd[k], s);
        tkm1 = tk;
        tk   = tn;
      }
      s4 += s;
    }
    acc[r] = s4;
  }

  // Cheap 4-row reduce: 2 xor levels on each acc, quarter-select, 4 xor levels.
#pragma unroll
  for (int r = 0; r < 4; ++r) {
    acc[r] += __shfl_xor(acc[r], 32, 64);
    acc[r] += __shfl_xor(acc[r], 16, 64);
  }
  // lanes 16r..16r+15 take row r's partials (register select, no indexing)
  float v = (lane < 32) ? ((lane < 16) ? acc[0] : acc[1])
                        : ((lane < 48) ? acc[2] : acc[3]);
#pragma unroll
  for (int off = 8; off; off >>= 1) v += __shfl_xor(v, off, 64);

  // lanes 0,16,32,48 write out[r0+0..3]: one coalesced 16B-wide masked store
  if ((lane & 15) == 0) out[r0 + (lane >> 4)] = v;
}

extern "C" void kernel_launch(void* const* d_in, const int* in_sizes, int n_in,
                              void* d_out, int out_size, void* d_ws, size_t ws_size,
                              hipStream_t stream) {
  const float* x      = (const float*)d_in[0];  // [32768, 256]
  const float* coeffs = (const float*)d_in[1];  // [256, 2304]
  const float* h      = (const float*)d_in[2];  // [256]
  float* out = (float*)d_out;                   // [32768]
  float* w   = (float*)d_ws;                    // [2304] scratch

  reduce_w_kernel<<<9, 1024, 0, stream>>>(coeffs, h, w);
  kan_main_kernel<<<2048, 256, 0, stream>>>(x, w, out);
}